// Round 1
// baseline (1105.790 us; speedup 1.0000x reference)
//
#include <hip/hip_runtime.h>
#include <cstdint>
#include <cstddef>

#define TEXTD 768
#define VISD  512
#define AUDD  128

__device__ __forceinline__ float wred_sum(float v){
  #pragma unroll
  for (int m = 32; m >= 1; m >>= 1) v += __shfl_xor(v, m, 64);
  return v;
}

// ---------------- projection: h0[n][64] = x[n,:dim] @ W_type + b_type ----------------
__global__ __launch_bounds__(256) void k_proj(const float* __restrict__ x,
    const int* __restrict__ ntype,
    const float* __restrict__ Wt, const float* __restrict__ bt,
    const float* __restrict__ Wv, const float* __restrict__ bv,
    const float* __restrict__ Wa, const float* __restrict__ ba,
    float* __restrict__ h0, int nN){
  int t = threadIdx.x;
  int n = blockIdx.x * 4 + (t >> 6);   // one wave per node -> no intra-wave divergence on type
  int j = t & 63;
  if (n >= nN) return;
  int ty = ntype[n];
  const float* W; const float* b; int dim;
  if (ty == 0)      { W = Wt; b = bt; dim = TEXTD; }
  else if (ty == 1) { W = Wv; b = bv; dim = VISD; }
  else              { W = Wa; b = ba; dim = AUDD; }
  const float* xr = x + (size_t)n * TEXTD;
  float acc = b[j];
  for (int k = 0; k < dim; k += 4){
    float4 xv = *reinterpret_cast<const float4*>(xr + k);
    acc += xv.x * W[(k+0)*64 + j];
    acc += xv.y * W[(k+1)*64 + j];
    acc += xv.z * W[(k+2)*64 + j];
    acc += xv.w * W[(k+3)*64 + j];
  }
  h0[(size_t)n*64 + j] = acc;
}

// ---------------- CSR build ----------------
__global__ void k_deg_init(int* __restrict__ deg, int nN){
  int i = blockIdx.x*blockDim.x + threadIdx.x;
  if (i < nN) deg[i] = 1;                    // self-loop
}
__global__ void k_deg_edges(const int* __restrict__ ei, int E, int* __restrict__ deg){
  int i = blockIdx.x*blockDim.x + threadIdx.x;
  if (i < E) atomicAdd(&deg[ei[E + i]], 1);  // dst row
}
// single-block exclusive scan (wave shfl scan, 16 waves of 64)
__global__ __launch_bounds__(1024) void k_scan(const int* __restrict__ deg, int* __restrict__ off, int n){
  __shared__ int wsum[16];
  __shared__ int carry_s;
  int t = threadIdx.x, lane = t & 63, w = t >> 6;
  if (t == 0) carry_s = 0;
  __syncthreads();
  for (int base = 0; base < n; base += 1024){
    int i = base + t;
    int v = (i < n) ? deg[i] : 0;
    int orig = v;
    #pragma unroll
    for (int o = 1; o < 64; o <<= 1){ int u = __shfl_up(v, o, 64); if (lane >= o) v += u; }
    if (lane == 63) wsum[w] = v;
    __syncthreads();
    if (t < 16){
      int xv = wsum[t];
      #pragma unroll
      for (int o = 1; o < 16; o <<= 1){ int u = __shfl_up(xv, o, 16); if (t >= o) xv += u; }
      wsum[t] = xv;
    }
    __syncthreads();
    int wbase = (w == 0) ? 0 : wsum[w-1];
    int incl = v + wbase;
    int carry = carry_s;
    if (i < n) off[i] = carry + incl - orig;
    __syncthreads();
    if (t == 0) carry_s = carry + wsum[15];
    __syncthreads();
  }
  if (threadIdx.x == 0) off[n] = carry_s;
}
__global__ void k_pos_copy(const int* __restrict__ off, int* __restrict__ pos, int nN){
  int i = blockIdx.x*blockDim.x + threadIdx.x;
  if (i < nN) pos[i] = off[i];
}
__global__ void k_scatter(const int* __restrict__ ei, int E, int nN,
                          int* __restrict__ pos, int* __restrict__ csr_src){
  int i = blockIdx.x*blockDim.x + threadIdx.x;
  int total = E + nN;
  if (i >= total) return;
  int s, d;
  if (i < E){ s = ei[i]; d = ei[E + i]; } else { s = i - E; d = s; }
  int p = atomicAdd(&pos[d], 1);
  csr_src[p] = s;
}

// ---------------- lin1: h1 = h0 @ W1 ; alpha1_s/d per head (wave reduce) ----------------
__global__ __launch_bounds__(256) void k_lin1(const float* __restrict__ h0,
    const float* __restrict__ W1, const float* __restrict__ a1s, const float* __restrict__ a1d,
    float* __restrict__ h1, float* __restrict__ as1, float* __restrict__ ad1, int nN){
  __shared__ float sW[64*256];   // 64 KB
  int t = threadIdx.x, lane = t & 63, w = t >> 6;
  for (int i = t; i < 64*256; i += 256) sW[i] = W1[i];
  __syncthreads();
  float avs[4], avd[4];
  #pragma unroll
  for (int r = 0; r < 4; r++){ avs[r] = a1s[r*64 + lane]; avd[r] = a1d[r*64 + lane]; }
  for (int nb = 0; nb < 8; nb++){
    int n = blockIdx.x*32 + nb*4 + w;      // one wave per node
    if (n >= nN) continue;
    const float* hr = h0 + (size_t)n*64;
    float acc[4] = {0.f,0.f,0.f,0.f};
    #pragma unroll 4
    for (int k = 0; k < 64; k += 4){
      float4 hv = *reinterpret_cast<const float4*>(hr + k);
      float hk[4] = {hv.x, hv.y, hv.z, hv.w};
      #pragma unroll
      for (int kk = 0; kk < 4; kk++){
        #pragma unroll
        for (int r = 0; r < 4; r++)
          acc[r] += hk[kk] * sW[(k+kk)*256 + r*64 + lane];
      }
    }
    #pragma unroll
    for (int r = 0; r < 4; r++) h1[(size_t)n*256 + r*64 + lane] = acc[r];
    #pragma unroll
    for (int r = 0; r < 4; r++){
      float vs = wred_sum(acc[r] * avs[r]);
      float vd = wred_sum(acc[r] * avd[r]);
      if (lane == 0){ as1[n*4 + r] = vs; ad1[n*4 + r] = vd; }
    }
  }
}

// ---------------- conv1 aggregate (gather, per-dst), + b1 + ELU -> g1[n][256] ----------------
__global__ __launch_bounds__(64) void k_gat1(const int* __restrict__ off, const int* __restrict__ srcs,
    const float* __restrict__ as1, const float* __restrict__ ad1,
    const float* __restrict__ h1, const float* __restrict__ b1,
    float* __restrict__ g1, int nN){
  int n = blockIdx.x;
  int c = threadIdx.x;
  float ad[4];
  {
    float4 a = *reinterpret_cast<const float4*>(ad1 + n*4);
    ad[0]=a.x; ad[1]=a.y; ad[2]=a.z; ad[3]=a.w;
  }
  int s0 = off[n], s1 = off[n+1];
  float m[4] = {-1e30f,-1e30f,-1e30f,-1e30f};
  for (int e = s0; e < s1; ++e){
    int s = srcs[e];
    float4 a = *reinterpret_cast<const float4*>(as1 + s*4);
    float av[4] = {a.x,a.y,a.z,a.w};
    #pragma unroll
    for (int h = 0; h < 4; h++){
      float v = av[h] + ad[h];
      v = (v > 0.f) ? v : 0.2f*v;
      m[h] = fmaxf(m[h], v);
    }
  }
  float den[4] = {0.f,0.f,0.f,0.f};
  float acc[4] = {0.f,0.f,0.f,0.f};
  for (int e = s0; e < s1; ++e){
    int s = srcs[e];
    float4 a = *reinterpret_cast<const float4*>(as1 + s*4);
    float av[4] = {a.x,a.y,a.z,a.w};
    const float* hp = h1 + (size_t)s*256;
    #pragma unroll
    for (int h = 0; h < 4; h++){
      float v = av[h] + ad[h];
      v = (v > 0.f) ? v : 0.2f*v;
      float p = expf(v - m[h]);
      den[h] += p;
      acc[h] += p * hp[h*64 + c];
    }
  }
  #pragma unroll
  for (int h = 0; h < 4; h++){
    float o = acc[h] / (den[h] + 1e-16f) + b1[h*64 + c];
    o = (o > 0.f) ? o : expm1f(o);          // ELU
    g1[(size_t)n*256 + h*64 + c] = o;
  }
}

// ---------------- lin2: h2 = g1 @ W2 ; alpha2_s/d ----------------
__global__ __launch_bounds__(256) void k_lin2(const float* __restrict__ g1,
    const float* __restrict__ W2, const float* __restrict__ a2s, const float* __restrict__ a2d,
    float* __restrict__ h2, float* __restrict__ as2, float* __restrict__ ad2, int nN){
  __shared__ float sW[256*64];   // 64 KB
  int t = threadIdx.x, lane = t & 63, w = t >> 6;
  for (int i = t; i < 256*64; i += 256) sW[i] = W2[i];
  __syncthreads();
  float a2sv = a2s[lane], a2dv = a2d[lane];
  for (int nb = 0; nb < 8; nb++){
    int n = blockIdx.x*32 + nb*4 + w;
    if (n >= nN) continue;
    const float* gr = g1 + (size_t)n*256;
    float acc = 0.f;
    #pragma unroll 4
    for (int k = 0; k < 256; k += 4){
      float4 gv = *reinterpret_cast<const float4*>(gr + k);
      acc += gv.x * sW[(k+0)*64 + lane];
      acc += gv.y * sW[(k+1)*64 + lane];
      acc += gv.z * sW[(k+2)*64 + lane];
      acc += gv.w * sW[(k+3)*64 + lane];
    }
    h2[(size_t)n*64 + lane] = acc;
    float vs = wred_sum(acc * a2sv);
    float vd = wred_sum(acc * a2dv);
    if (lane == 0){ as2[n] = vs; ad2[n] = vd; }
  }
}

// ---------------- conv2 aggregate + b2, fused batch pooling ----------------
__global__ __launch_bounds__(64) void k_gat2(const int* __restrict__ off, const int* __restrict__ srcs,
    const float* __restrict__ as2, const float* __restrict__ ad2,
    const float* __restrict__ h2, const float* __restrict__ b2,
    const int* __restrict__ batch, float* __restrict__ pool, int* __restrict__ cnt, int nN){
  int n = blockIdx.x;
  int c = threadIdx.x;
  float ad = ad2[n];
  int s0 = off[n], s1 = off[n+1];
  float m = -1e30f;
  for (int e = s0; e < s1; ++e){
    int s = srcs[e];
    float v = as2[s] + ad;
    v = (v > 0.f) ? v : 0.2f*v;
    m = fmaxf(m, v);
  }
  float den = 0.f, acc = 0.f;
  for (int e = s0; e < s1; ++e){
    int s = srcs[e];
    float v = as2[s] + ad;
    v = (v > 0.f) ? v : 0.2f*v;
    float p = expf(v - m);
    den += p;
    acc += p * h2[(size_t)s*64 + c];
  }
  float o = acc / (den + 1e-16f) + b2[c];
  int bb = batch[n];
  atomicAdd(&pool[bb*64 + c], o);
  if (c == 0) atomicAdd(&cnt[bb], 1);
}

// ---------------- final: out[b] = (pool[b]/max(cnt,1)) @ Wl + bl ----------------
__global__ __launch_bounds__(64) void k_final(const float* __restrict__ pool, const int* __restrict__ cnt,
    const float* __restrict__ Wl, const float* __restrict__ bl, float* __restrict__ out, int B){
  int b = blockIdx.x, c = threadIdx.x;
  float cn = fmaxf((float)cnt[b], 1.0f);
  float g = pool[b*64 + c] / cn;
  float v = wred_sum(g * Wl[c]);
  if (c == 0) out[b] = v + bl[0];
}

extern "C" void kernel_launch(void* const* d_in, const int* in_sizes, int n_in,
                              void* d_out, int out_size, void* d_ws, size_t ws_size,
                              hipStream_t stream){
  const float* x    = (const float*)d_in[0];
  const int*   ntyp = (const int*)  d_in[1];
  const int*   ei   = (const int*)  d_in[2];
  const int*   batch= (const int*)  d_in[3];
  const float* Wt = (const float*)d_in[4];
  const float* bt = (const float*)d_in[5];
  const float* Wv = (const float*)d_in[6];
  const float* bv = (const float*)d_in[7];
  const float* Wa = (const float*)d_in[8];
  const float* ba = (const float*)d_in[9];
  const float* W1 = (const float*)d_in[10];
  const float* a1s= (const float*)d_in[11];
  const float* a1d= (const float*)d_in[12];
  const float* b1 = (const float*)d_in[13];
  const float* W2 = (const float*)d_in[14];
  const float* a2s= (const float*)d_in[15];
  const float* a2d= (const float*)d_in[16];
  const float* b2 = (const float*)d_in[17];
  const float* Wl = (const float*)d_in[18];
  const float* bl = (const float*)d_in[19];

  const int N = in_sizes[1];
  const int E = in_sizes[2] / 2;
  const int B = out_size;

  char* ws = (char*)d_ws;
  size_t o = 0;
  auto alloc = [&](size_t bytes) -> void* {
    void* p = ws + o;
    o = (o + bytes + 255) & ~(size_t)255;
    return p;
  };
  int*   csr_off = (int*)  alloc((size_t)(N+1)*4);
  int*   pos     = (int*)  alloc((size_t)N*4);
  int*   csr_src = (int*)  alloc((size_t)(E+N)*4);
  float* as1     = (float*)alloc((size_t)N*4*4);
  float* ad1     = (float*)alloc((size_t)N*4*4);
  float* h0      = (float*)alloc((size_t)N*64*4);
  float* h1      = (float*)alloc((size_t)N*256*4);
  float* g1      = (float*)alloc((size_t)N*256*4);
  float* pool    = (float*)alloc((size_t)B*64*4);
  int*   cnt     = (int*)  alloc((size_t)B*4);
  // aliases (dead-after relationships): h2 reuses h0; alpha2 reuses alpha1
  float* h2  = h0;        // h0 dead after k_lin1
  float* as2 = as1;       // as1/ad1 dead after k_gat1
  float* ad2 = ad1;

  hipMemsetAsync(pool, 0, (size_t)B*64*4, stream);
  hipMemsetAsync(cnt,  0, (size_t)B*4,    stream);

  k_proj<<<(N + 3)/4, 256, 0, stream>>>(x, ntyp, Wt, bt, Wv, bv, Wa, ba, h0, N);

  k_deg_init <<<(N + 255)/256, 256, 0, stream>>>(pos, N);
  k_deg_edges<<<(E + 255)/256, 256, 0, stream>>>(ei, E, pos);
  k_scan     <<<1, 1024, 0, stream>>>(pos, csr_off, N);
  k_pos_copy <<<(N + 255)/256, 256, 0, stream>>>(csr_off, pos, N);
  k_scatter  <<<(E + N + 255)/256, 256, 0, stream>>>(ei, E, N, pos, csr_src);

  k_lin1<<<(N + 31)/32, 256, 0, stream>>>(h0, W1, a1s, a1d, h1, as1, ad1, N);
  k_gat1<<<N, 64, 0, stream>>>(csr_off, csr_src, as1, ad1, h1, b1, g1, N);
  k_lin2<<<(N + 31)/32, 256, 0, stream>>>(g1, W2, a2s, a2d, h2, as2, ad2, N);
  k_gat2<<<N, 64, 0, stream>>>(csr_off, csr_src, as2, ad2, h2, b2, batch, pool, cnt, N);
  k_final<<<B, 64, 0, stream>>>(pool, cnt, Wl, bl, (float*)d_out, B);
}